// Round 3
// baseline (664.257 us; speedup 1.0000x reference)
//
#include <hip/hip_runtime.h>

// GCN layer: out = PReLU( SpMM(A, x @ W^T + b) )
// R7: gemm rewritten — 512 threads / 8 waves of 64x64 (acc 64 VGPR ->
// launch_bounds(512,4) = 16 waves/CU), B-fragments loaded directly from
// L2-resident Wbf (no Bs staging), A software-pipelined via register
// prefetch. spmm/partition/binsort unchanged (spmm pinned at ~3.9 TB/s
// L2-miss wall across two different schedules -> structural).

#define K_DIM 512
#define H_DIM 256

#define BIN_ROWS 512        // rows per bin
#define NBIN_MAX 256        // LDS array size; runtime nbins = 196
#define EB 18432            // per-bin edge capacity (mean 16384, sigma ~128)
#define P1_CHUNK 4096       // edges per partition block
#define P1_PER_T 4          // P1_CHUNK / 1024
#define SPU 8               // spmm gather batch

typedef __attribute__((ext_vector_type(8))) short short8;
typedef __attribute__((ext_vector_type(4))) float floatx4;

__device__ inline short f32_to_bf16(float f) {
    unsigned u = __float_as_uint(f);
    u += 0x7fffu + ((u >> 16) & 1u);    // round-to-nearest-even
    return (short)(u >> 16);
}
__device__ inline float bf16_to_f32(unsigned short u) {
    return __uint_as_float(((unsigned)u) << 16);
}

// ---------------- W pre-convert: fp32 -> bf16 (once, 131072 elems) ----------
__global__ __launch_bounds__(256) void convert_w_kernel(
    const float* __restrict__ W, unsigned short* __restrict__ Wbf)
{
    int i = (blockIdx.x * 256 + threadIdx.x) * 8;   // grid sized exactly
    float4 a = *(const float4*)(W + i);
    float4 b = *(const float4*)(W + i + 4);
    short8 v;
    v[0] = f32_to_bf16(a.x); v[1] = f32_to_bf16(a.y);
    v[2] = f32_to_bf16(a.z); v[3] = f32_to_bf16(a.w);
    v[4] = f32_to_bf16(b.x); v[5] = f32_to_bf16(b.y);
    v[6] = f32_to_bf16(b.z); v[7] = f32_to_bf16(b.w);
    *(short8*)((short*)Wbf + i) = v;
}

// ---------------- GEMM: h(bf16) = x @ W^T + b ----------------
// 512 threads = 8 waves (2M x 4N), wave tile 64x64, block tile 128x256.
// A: fp32->bf16 staged in LDS (8 KB) with register prefetch pipeline.
// B: fragments loaded directly from global (Wbf is 256 KB, L2-resident).
#define GT_M 128
#define GT_K 32
#define NSTEP (K_DIM / GT_K)   // 16
#define LDSW 32   // shorts per LDS row (64 B stride: b128 reads evenly banked)

__global__ __launch_bounds__(512, 4) void gemm_bf16_kernel(
    const float* __restrict__ A,             // x [M, 512] fp32
    const unsigned short* __restrict__ Wbf,  // [256, 512] bf16
    const float* __restrict__ bias,          // [256]
    unsigned short* __restrict__ H,          // h bf16 [M, 256]
    int M)
{
    __shared__ short As[GT_M * LDSW];   // 8 KB

    const int tid  = threadIdx.x;
    const int m0   = blockIdx.x * GT_M;

    const int wave = tid >> 6;            // 0..7
    const int lane = tid & 63;
    const int wm   = (wave >> 2) * 64;    // 0 or 64
    const int wn   = (wave & 3) * 64;     // 0,64,128,192
    const int quad = lane >> 4;
    const int l16  = lane & 15;

    const int arow  = tid >> 2;   // 0..127
    const int apart = tid & 3;    // 8-float part of the 32-k tile

    floatx4 acc[4][4] = {};

    const bool arow_ok = (m0 + arow) < M;
    const float* asrc = A + (size_t)(m0 + arow) * K_DIM + apart * 8;

    // prologue: load A regs for ks = 0
    float f[8];
    if (arow_ok) {
        *(float4*)(f + 0) = *(const float4*)(asrc + 0);
        *(float4*)(f + 4) = *(const float4*)(asrc + 4);
    } else {
        #pragma unroll
        for (int j = 0; j < 8; ++j) f[j] = 0.f;
    }

    for (int ks = 0; ks < NSTEP; ++ks) {
        // convert + write A tile to LDS
        short8 v;
        #pragma unroll
        for (int j = 0; j < 8; ++j) v[j] = f32_to_bf16(f[j]);
        *(short8*)&As[arow * LDSW + apart * 8] = v;
        __syncthreads();

        // register prefetch of next A tile (consumed after next barrier)
        if (ks + 1 < NSTEP && arow_ok) {
            const float* s2 = asrc + (ks + 1) * GT_K;
            *(float4*)(f + 0) = *(const float4*)(s2 + 0);
            *(float4*)(f + 4) = *(const float4*)(s2 + 4);
        }

        // B fragments straight from global (L2-hit)
        short8 bf[4];
        const int kb = ks * GT_K + quad * 8;
        #pragma unroll
        for (int t = 0; t < 4; ++t)
            bf[t] = *(const short8*)(Wbf + (size_t)(wn + t * 16 + l16) * K_DIM + kb);

        // A fragments from LDS
        short8 af[4];
        #pragma unroll
        for (int t = 0; t < 4; ++t)
            af[t] = *(const short8*)&As[(wm + t * 16 + l16) * LDSW + quad * 8];

        #pragma unroll
        for (int i = 0; i < 4; ++i)
            #pragma unroll
            for (int j = 0; j < 4; ++j)
                acc[i][j] = __builtin_amdgcn_mfma_f32_16x16x32_bf16(af[i], bf[j], acc[i][j], 0, 0, 0);
        __syncthreads();
    }

    // ---- epilogue: + bias, fp32 -> bf16, store ----
    // C/D layout: col = lane&15, row = quad*4 + reg
    #pragma unroll
    for (int j = 0; j < 4; ++j) {
        int gcol = wn + j * 16 + l16;
        float bj = bias[gcol];
        #pragma unroll
        for (int i = 0; i < 4; ++i) {
            int rbase = m0 + wm + i * 16 + quad * 4;
            #pragma unroll
            for (int r = 0; r < 4; ++r) {
                int gm = rbase + r;
                if (gm < M)
                    H[(size_t)gm * H_DIM + gcol] =
                        (unsigned short)f32_to_bf16(acc[i][j][r] + bj);
            }
        }
    }
}

// ---------------- P1: partition edges into 512-row bins ----------------
__global__ __launch_bounds__(1024) void partition_kernel(
    const int* __restrict__ rows, const int* __restrict__ cols,
    const float* __restrict__ vals, int* __restrict__ binCursor,
    int2* __restrict__ binned, int E, int nbins)
{
    __shared__ int hist[NBIN_MAX];
    __shared__ int binOff[NBIN_MAX];
    __shared__ int gbase[NBIN_MAX];
    __shared__ int cursor[NBIN_MAX];
    __shared__ int sc[2][NBIN_MAX];
    __shared__ int2 stage[P1_CHUNK];               // 32 KB
    __shared__ unsigned char binOf[P1_CHUNK];      // 4 KB

    const int tid = threadIdx.x;
    const int e0  = blockIdx.x * P1_CHUNK;
    const int total = min(P1_CHUNK, E - e0);       // # valid edges this chunk

    int r[P1_PER_T], c[P1_PER_T];
    float v[P1_PER_T];
    #pragma unroll
    for (int i = 0; i < P1_PER_T; ++i) {
        int e = e0 + tid + i * 1024;
        if (e < E) { r[i] = rows[e]; c[i] = cols[e]; v[i] = vals[e]; }
        else       { r[i] = -1; c[i] = 0; v[i] = 0.f; }
    }

    if (tid < NBIN_MAX) hist[tid] = 0;
    __syncthreads();
    #pragma unroll
    for (int i = 0; i < P1_PER_T; ++i)
        if (r[i] >= 0) atomicAdd(&hist[r[i] >> 9], 1);
    __syncthreads();

    // exclusive scan over 256 bin slots (threads < 256; Hillis-Steele)
    if (tid < NBIN_MAX) sc[0][tid] = hist[tid];
    __syncthreads();
    int cur = 0;
    for (int d = 1; d < NBIN_MAX; d <<= 1) {
        if (tid < NBIN_MAX) {
            int y = sc[cur][tid];
            if (tid >= d) y += sc[cur][tid - d];
            sc[cur ^ 1][tid] = y;
        }
        __syncthreads();
        cur ^= 1;
    }
    if (tid < NBIN_MAX) {
        int x    = hist[tid];
        int excl = sc[cur][tid] - x;
        binOff[tid] = excl;
        cursor[tid] = excl;
        if (tid < nbins) gbase[tid] = atomicAdd(&binCursor[tid], x);  // 196 atomics/block
        else             gbase[tid] = 0;
    }
    __syncthreads();

    // regroup edges by bin in LDS
    #pragma unroll
    for (int i = 0; i < P1_PER_T; ++i) {
        if (r[i] >= 0) {
            int bin  = r[i] >> 9;
            int lpos = atomicAdd(&cursor[bin], 1);
            stage[lpos] = make_int2(((r[i] & (BIN_ROWS - 1)) << 17) | c[i],
                                    __float_as_int(v[i]));
            binOf[lpos] = (unsigned char)bin;
        }
    }
    __syncthreads();

    // coalesced copy-out: consecutive idx in same bin -> consecutive gaddr
    #pragma unroll
    for (int i = 0; i < P1_PER_T; ++i) {
        int idx = tid + i * 1024;
        if (idx < total) {
            int bin = binOf[idx];
            int rel = gbase[bin] + (idx - binOff[bin]);
            if (rel < EB)
                binned[(size_t)bin * EB + rel] = stage[idx];
        }
    }
}

// ---------------- P2: per-bin counting sort -> CSR runs ----------------
__global__ __launch_bounds__(1024) void binsort_kernel(
    const int2* __restrict__ binned, const int* __restrict__ binCursor,
    int2* __restrict__ sorted, int* __restrict__ rowstart,
    int* __restrict__ degArr, int M)
{
    __shared__ int hist[BIN_ROWS];
    __shared__ int cursor[BIN_ROWS];
    __shared__ int sc[2][BIN_ROWS];

    const int b   = blockIdx.x;
    const int tid = threadIdx.x;
    int cnt = binCursor[b]; if (cnt > EB) cnt = EB;
    int rows_here = M - b * BIN_ROWS; if (rows_here > BIN_ROWS) rows_here = BIN_ROWS;

    if (tid < BIN_ROWS) hist[tid] = 0;
    __syncthreads();
    const int2* src = binned + (size_t)b * EB;
    for (int i = tid; i < cnt; i += 1024)
        atomicAdd(&hist[((unsigned)src[i].x) >> 17], 1);
    __syncthreads();

    if (tid < BIN_ROWS) sc[0][tid] = hist[tid];
    __syncthreads();
    int cur = 0;
    for (int d = 1; d < BIN_ROWS; d <<= 1) {
        if (tid < BIN_ROWS) {
            int y = sc[cur][tid];
            if (tid >= d) y += sc[cur][tid - d];
            sc[cur ^ 1][tid] = y;
        }
        __syncthreads();
        cur ^= 1;
    }
    if (tid < BIN_ROWS) {
        int x    = hist[tid];
        int excl = sc[cur][tid] - x;
        cursor[tid] = excl;
        if (tid < rows_here) {
            rowstart[b * BIN_ROWS + tid] = b * EB + excl;   // absolute index
            degArr[b * BIN_ROWS + tid]   = x;
        }
    }
    __syncthreads();

    int2* dst = sorted + (size_t)b * EB;
    for (int i = tid; i < cnt; i += 1024) {
        int2 p  = src[i];                               // L2-hot re-read
        int rl  = ((unsigned)p.x) >> 17;
        int pos = atomicAdd(&cursor[rl], 1);
        dst[pos] = make_int2(p.x & 0x1FFFF, p.y);       // scatter into L2-resident window
    }
}

// ---------------- SpMM gather (bf16 h) + PReLU ----------------
__global__ __launch_bounds__(256) void spmm_gather_kernel(
    const unsigned short* __restrict__ h, const int* __restrict__ rowstart,
    const int* __restrict__ degArr, const int2* __restrict__ sorted,
    const float* __restrict__ alpha_p, float* __restrict__ out, int M)
{
    const int wave = threadIdx.x >> 6;
    const int lane = threadIdx.x & 63;
    const int row = blockIdx.x * 4 + wave;
    if (row >= M) return;

    const int deg = degArr[row];
    const int2* ep = sorted + rowstart[row];

    float4 acc = make_float4(0.f, 0.f, 0.f, 0.f);

    for (int chunk = 0; chunk < deg; chunk += 64) {
        int rem = deg - chunk;
        int n   = rem < 64 ? rem : 64;
        int ru  = (n + SPU - 1) & ~(SPU - 1);            // pad to batch; pads have val=0
        int2 p  = (chunk + lane < deg) ? ep[chunk + lane] : make_int2(0, 0);

        ushort4 u[SPU]; float vv[SPU];
        #pragma unroll
        for (int j = 0; j < SPU; ++j) {
            int c  = __shfl(p.x, j);
            vv[j]  = __int_as_float(__shfl(p.y, j));
            u[j]   = *(const ushort4*)(h + (size_t)c * H_DIM + lane * 4);
        }
        for (int e = SPU; e < ru; e += SPU) {
            ushort4 u2[SPU]; float vv2[SPU];
            #pragma unroll
            for (int j = 0; j < SPU; ++j) {
                int c   = __shfl(p.x, e + j);
                vv2[j]  = __int_as_float(__shfl(p.y, e + j));
                u2[j]   = *(const ushort4*)(h + (size_t)c * H_DIM + lane * 4);
            }
            #pragma unroll
            for (int j = 0; j < SPU; ++j) {
                float v = vv[j];
                acc.x += v * bf16_to_f32(u[j].x);
                acc.y += v * bf16_to_f32(u[j].y);
                acc.z += v * bf16_to_f32(u[j].z);
                acc.w += v * bf16_to_f32(u[j].w);
            }
            #pragma unroll
            for (int j = 0; j < SPU; ++j) { u[j] = u2[j]; vv[j] = vv2[j]; }
        }
        #pragma unroll
        for (int j = 0; j < SPU; ++j) {
            float v = vv[j];
            acc.x += v * bf16_to_f32(u[j].x);
            acc.y += v * bf16_to_f32(u[j].y);
            acc.z += v * bf16_to_f32(u[j].z);
            acc.w += v * bf16_to_f32(u[j].w);
        }
    }

    const float alpha = *alpha_p;
    acc.x = acc.x >= 0.f ? acc.x : alpha * acc.x;
    acc.y = acc.y >= 0.f ? acc.y : alpha * acc.y;
    acc.z = acc.z >= 0.f ? acc.z : alpha * acc.z;
    acc.w = acc.w >= 0.f ? acc.w : alpha * acc.w;
    *(float4*)(out + (size_t)row * H_DIM + lane * 4) = acc;
}

extern "C" void kernel_launch(void* const* d_in, const int* in_sizes, int n_in,
                              void* d_out, int out_size, void* d_ws, size_t ws_size,
                              hipStream_t stream) {
    const float* x        = (const float*)d_in[0];
    const int*   adj_rows = (const int*)d_in[1];
    const int*   adj_cols = (const int*)d_in[2];
    const float* adj_vals = (const float*)d_in[3];
    const float* W        = (const float*)d_in[4];
    const float* b        = (const float*)d_in[5];
    const float* alpha    = (const float*)d_in[6];
    float* out = (float*)d_out;

    const int M = in_sizes[0] / K_DIM;   // 100000
    const int E = in_sizes[1];           // 3200000
    const int nbins = (M + BIN_ROWS - 1) / BIN_ROWS;   // 196 (<= NBIN_MAX)

    char* ws = (char*)d_ws;
    size_t off = 0;
    auto alloc = [&](size_t bytes) {
        char* p = ws + off;
        off += (bytes + 255) & ~(size_t)255;
        return p;
    };
    unsigned short* h = (unsigned short*)alloc((size_t)M * H_DIM * sizeof(unsigned short)); // 51.2 MB
    int2* binned  = (int2*)alloc((size_t)nbins * EB * sizeof(int2));   // 28.9 MB
    int2* sorted  = (int2*)alloc((size_t)nbins * EB * sizeof(int2));   // 28.9 MB
    int*  rowstart = (int*)alloc((size_t)M * sizeof(int));             // 0.4 MB
    int*  degArr   = (int*)alloc((size_t)M * sizeof(int));             // 0.4 MB
    int*  binCursor = (int*)alloc((size_t)NBIN_MAX * sizeof(int));     // 1 KB
    unsigned short* Wbf = (unsigned short*)alloc((size_t)H_DIM * K_DIM * sizeof(unsigned short)); // 256 KB

    // 0) W -> bf16 once (131072 elems / 8 per thread / 256 per block = 64 blocks)
    convert_w_kernel<<<64, 256, 0, stream>>>(W, Wbf);

    // 1) h = bf16( x @ W^T + b )  via MFMA, full H per block
    gemm_bf16_kernel<<<dim3((M + GT_M - 1) / GT_M, 1), 512, 0, stream>>>(x, Wbf, b, h, M);

    // 2) partition edges into 512-row bins (write-combined)
    hipMemsetAsync(binCursor, 0, (size_t)NBIN_MAX * sizeof(int), stream);
    partition_kernel<<<(E + P1_CHUNK - 1) / P1_CHUNK, 1024, 0, stream>>>(
        adj_rows, adj_cols, adj_vals, binCursor, binned, E, nbins);

    // 3) per-bin counting sort -> contiguous per-row runs + rowstart/deg
    binsort_kernel<<<nbins, 1024, 0, stream>>>(binned, binCursor, sorted,
                                               rowstart, degArr, M);

    // 4) SpMM gather + PReLU, one wave per row
    spmm_gather_kernel<<<(M + 3) / 4, 256, 0, stream>>>(h, rowstart, degArr, sorted,
                                                        alpha, out, M);
}

// Round 4
// 643.473 us; speedup vs baseline: 1.0323x; 1.0323x over previous
//
#include <hip/hip_runtime.h>

// GCN layer: out = PReLU( SpMM(A, x @ W^T + b) )
// R8: (a) gemm: B staged via LDS with fully-coalesced mapping (R7's direct
//     global B-frags were a 64-line scatter = ~1.6 GB L2->L1 thrash);
//     both A and B register-prefetched one K-step ahead, 512 thr / 8 waves.
// (b) P2 (binsort) FUSED into spmm: block = half-bin (256 rows), counting
//     sort ~8K edges into 72 KB LDS, then 8 waves gather straight from the
//     LDS run table. Kills the 51 MB sorted/rowstart/deg HBM round-trip,
//     one launch, and P2's 196-block underfill.
// (c) P1 at 512 threads (3 blocks/CU by LDS).

#define K_DIM 512
#define H_DIM 256

#define BIN_ROWS 512        // rows per bin
#define NBIN_MAX 256        // LDS array size; runtime nbins = 196
#define EB 18432            // per-bin edge capacity (mean 16384, +16 sigma)
#define P1_CHUNK 4096       // edges per partition block
#define P1_PER_T 8          // P1_CHUNK / 512
#define HALF_ROWS 256       // rows per fused-spmm block
#define SCAP 9216           // LDS run-table capacity (mean 8192, +11 sigma)

typedef __attribute__((ext_vector_type(8))) short short8;
typedef __attribute__((ext_vector_type(4))) float floatx4;

__device__ inline short f32_to_bf16(float f) {
    unsigned u = __float_as_uint(f);
    u += 0x7fffu + ((u >> 16) & 1u);    // round-to-nearest-even
    return (short)(u >> 16);
}
__device__ inline float bf16_to_f32(unsigned short u) {
    return __uint_as_float(((unsigned)u) << 16);
}

// ---------------- W pre-convert: fp32 -> bf16 (once, 131072 elems) ----------
__global__ __launch_bounds__(256) void convert_w_kernel(
    const float* __restrict__ W, unsigned short* __restrict__ Wbf)
{
    int i = (blockIdx.x * 256 + threadIdx.x) * 8;   // grid sized exactly
    float4 a = *(const float4*)(W + i);
    float4 b = *(const float4*)(W + i + 4);
    short8 v;
    v[0] = f32_to_bf16(a.x); v[1] = f32_to_bf16(a.y);
    v[2] = f32_to_bf16(a.z); v[3] = f32_to_bf16(a.w);
    v[4] = f32_to_bf16(b.x); v[5] = f32_to_bf16(b.y);
    v[6] = f32_to_bf16(b.z); v[7] = f32_to_bf16(b.w);
    *(short8*)((short*)Wbf + i) = v;
}

// ---------------- GEMM: h(bf16) = x @ W^T + b ----------------
// 512 threads = 8 waves (2M x 4N), wave tile 64x64, block tile 128x256.
// A (fp32->bf16) and B (bf16 copy) staged in LDS, both register-prefetched
// one K-step ahead. All global loads fully coalesced (4 lanes x 16B per line).
#define GT_M 128
#define GT_K 32
#define NSTEP (K_DIM / GT_K)   // 16
#define LDSW 32   // shorts per LDS row

__global__ __launch_bounds__(512, 4) void gemm_bf16_kernel(
    const float* __restrict__ A,             // x [M, 512] fp32
    const unsigned short* __restrict__ Wbf,  // [256, 512] bf16
    const float* __restrict__ bias,          // [256]
    unsigned short* __restrict__ H,          // h bf16 [M, 256]
    int M)
{
    __shared__ short As[GT_M * LDSW];   // 8 KB
    __shared__ short Bs[256 * LDSW];    // 16 KB

    const int tid  = threadIdx.x;
    const int m0   = blockIdx.x * GT_M;

    const int wave = tid >> 6;            // 0..7
    const int lane = tid & 63;
    const int wm   = (wave >> 2) * 64;    // 0 or 64
    const int wn   = (wave & 3) * 64;     // 0,64,128,192
    const int quad = lane >> 4;
    const int l16  = lane & 15;

    const int arow = tid >> 2;   // 0..127
    const int seg  = tid & 3;    // 8-elem segment within the 32-k tile

    floatx4 acc[4][4] = {};

    const bool arow_ok = (m0 + arow) < M;
    const float* asrc = A + (size_t)(m0 + arow) * K_DIM + seg * 8;
    const unsigned short* bsrc = Wbf + (size_t)arow * K_DIM + seg * 8;  // rows arow, arow+128

    // prologue: load regs for ks = 0
    float f[8];
    short8 g0, g1;
    if (arow_ok) {
        *(float4*)(f + 0) = *(const float4*)(asrc + 0);
        *(float4*)(f + 4) = *(const float4*)(asrc + 4);
    } else {
        #pragma unroll
        for (int j = 0; j < 8; ++j) f[j] = 0.f;
    }
    g0 = *(const short8*)(bsrc);
    g1 = *(const short8*)(bsrc + 128 * K_DIM);

    for (int ks = 0; ks < NSTEP; ++ks) {
        // write staged tiles to LDS
        short8 v;
        #pragma unroll
        for (int j = 0; j < 8; ++j) v[j] = f32_to_bf16(f[j]);
        *(short8*)&As[arow * LDSW + seg * 8] = v;
        *(short8*)&Bs[arow * LDSW + seg * 8] = g0;
        *(short8*)&Bs[(arow + 128) * LDSW + seg * 8] = g1;
        __syncthreads();

        // register prefetch of next K-step (consumed after next barrier)
        if (ks + 1 < NSTEP) {
            if (arow_ok) {
                const float* s2 = asrc + (ks + 1) * GT_K;
                *(float4*)(f + 0) = *(const float4*)(s2 + 0);
                *(float4*)(f + 4) = *(const float4*)(s2 + 4);
            }
            const unsigned short* b2 = bsrc + (ks + 1) * GT_K;
            g0 = *(const short8*)(b2);
            g1 = *(const short8*)(b2 + 128 * K_DIM);
        }

        // fragments from LDS + 16 MFMA per wave
        short8 af[4], bf[4];
        #pragma unroll
        for (int t = 0; t < 4; ++t)
            af[t] = *(const short8*)&As[(wm + t * 16 + l16) * LDSW + quad * 8];
        #pragma unroll
        for (int t = 0; t < 4; ++t)
            bf[t] = *(const short8*)&Bs[(wn + t * 16 + l16) * LDSW + quad * 8];
        #pragma unroll
        for (int i = 0; i < 4; ++i)
            #pragma unroll
            for (int j = 0; j < 4; ++j)
                acc[i][j] = __builtin_amdgcn_mfma_f32_16x16x32_bf16(af[i], bf[j], acc[i][j], 0, 0, 0);
        __syncthreads();
    }

    // ---- epilogue: + bias, fp32 -> bf16, store ----
    // C/D layout: col = lane&15, row = quad*4 + reg
    #pragma unroll
    for (int j = 0; j < 4; ++j) {
        int gcol = wn + j * 16 + l16;
        float bj = bias[gcol];
        #pragma unroll
        for (int i = 0; i < 4; ++i) {
            int rbase = m0 + wm + i * 16 + quad * 4;
            #pragma unroll
            for (int r = 0; r < 4; ++r) {
                int gm = rbase + r;
                if (gm < M)
                    H[(size_t)gm * H_DIM + gcol] =
                        (unsigned short)f32_to_bf16(acc[i][j][r] + bj);
            }
        }
    }
}

// ---------------- P1: partition edges into 512-row bins ----------------
// LDS write-combining: histogram -> scan -> one global atomic per bin ->
// regroup in LDS -> coalesced run writes to per-bin buffers.
__global__ __launch_bounds__(512) void partition_kernel(
    const int* __restrict__ rows, const int* __restrict__ cols,
    const float* __restrict__ vals, int* __restrict__ binCursor,
    int2* __restrict__ binned, int E, int nbins)
{
    __shared__ int hist[NBIN_MAX];
    __shared__ int binOff[NBIN_MAX];
    __shared__ int gbase[NBIN_MAX];
    __shared__ int cursor[NBIN_MAX];
    __shared__ int sc[2][NBIN_MAX];
    __shared__ int2 stage[P1_CHUNK];               // 32 KB
    __shared__ unsigned char binOf[P1_CHUNK];      // 4 KB

    const int tid = threadIdx.x;
    const int e0  = blockIdx.x * P1_CHUNK;
    const int total = min(P1_CHUNK, E - e0);       // # valid edges this chunk

    int r[P1_PER_T], c[P1_PER_T];
    float v[P1_PER_T];
    #pragma unroll
    for (int i = 0; i < P1_PER_T; ++i) {
        int e = e0 + tid + i * 512;
        if (e < E) { r[i] = rows[e]; c[i] = cols[e]; v[i] = vals[e]; }
        else       { r[i] = -1; c[i] = 0; v[i] = 0.f; }
    }

    if (tid < NBIN_MAX) hist[tid] = 0;
    __syncthreads();
    #pragma unroll
    for (int i = 0; i < P1_PER_T; ++i)
        if (r[i] >= 0) atomicAdd(&hist[r[i] >> 9], 1);
    __syncthreads();

    // exclusive scan over 256 bin slots (threads < 256; Hillis-Steele)
    if (tid < NBIN_MAX) sc[0][tid] = hist[tid];
    __syncthreads();
    int cur = 0;
    for (int d = 1; d < NBIN_MAX; d <<= 1) {
        if (tid < NBIN_MAX) {
            int y = sc[cur][tid];
            if (tid >= d) y += sc[cur][tid - d];
            sc[cur ^ 1][tid] = y;
        }
        __syncthreads();
        cur ^= 1;
    }
    if (tid < NBIN_MAX) {
        int x    = hist[tid];
        int excl = sc[cur][tid] - x;
        binOff[tid] = excl;
        cursor[tid] = excl;
        if (tid < nbins) gbase[tid] = atomicAdd(&binCursor[tid], x);  // 196 atomics/block
        else             gbase[tid] = 0;
    }
    __syncthreads();

    // regroup edges by bin in LDS
    #pragma unroll
    for (int i = 0; i < P1_PER_T; ++i) {
        if (r[i] >= 0) {
            int bin  = r[i] >> 9;
            int lpos = atomicAdd(&cursor[bin], 1);
            stage[lpos] = make_int2(((r[i] & (BIN_ROWS - 1)) << 17) | c[i],
                                    __float_as_int(v[i]));
            binOf[lpos] = (unsigned char)bin;
        }
    }
    __syncthreads();

    // coalesced copy-out: consecutive idx in same bin -> consecutive gaddr
    #pragma unroll
    for (int i = 0; i < P1_PER_T; ++i) {
        int idx = tid + i * 512;
        if (idx < total) {
            int bin = binOf[idx];
            int rel = gbase[bin] + (idx - binOff[bin]);
            if (rel < EB)
                binned[(size_t)bin * EB + rel] = stage[idx];
        }
    }
}

// ---------------- fused binsort + SpMM gather + PReLU ----------------
// Block = half-bin (256 rows). Counting-sort the half's ~8K edges into a
// 72 KB LDS run table, then 8 waves gather: wave w handles rows w, w+8, ...
// reading (col,val) runs from LDS (broadcast reads, conflict-free).
__global__ __launch_bounds__(512, 2) void spmm_bin_kernel(
    const int2* __restrict__ binned, const int* __restrict__ binCursor,
    const unsigned short* __restrict__ h, const float* __restrict__ alpha_p,
    float* __restrict__ out, int M)
{
    __shared__ int2 run[SCAP];            // 72 KB
    __shared__ int hist[HALF_ROWS];
    __shared__ int rstart[HALF_ROWS];
    __shared__ int cursor[HALF_ROWS];
    __shared__ int sc[2][HALF_ROWS];

    const int b    = blockIdx.x >> 1;
    const int half = blockIdx.x & 1;
    const int tid  = threadIdx.x;
    int cnt = binCursor[b]; if (cnt > EB) cnt = EB;

    if (tid < HALF_ROWS) hist[tid] = 0;
    __syncthreads();

    const int2* src = binned + (size_t)b * EB;
    // pass 1: histogram of rows in my half
    for (int i = tid; i < cnt; i += 512) {
        int rl = ((unsigned)src[i].x) >> 17;
        if ((rl >> 8) == half) atomicAdd(&hist[rl & 255], 1);
    }
    __syncthreads();

    // exclusive scan over 256 rows
    if (tid < HALF_ROWS) sc[0][tid] = hist[tid];
    __syncthreads();
    int cur = 0;
    for (int d = 1; d < HALF_ROWS; d <<= 1) {
        if (tid < HALF_ROWS) {
            int y = sc[cur][tid];
            if (tid >= d) y += sc[cur][tid - d];
            sc[cur ^ 1][tid] = y;
        }
        __syncthreads();
        cur ^= 1;
    }
    if (tid < HALF_ROWS) {
        int excl = sc[cur][tid] - hist[tid];
        rstart[tid] = excl;
        cursor[tid] = excl;
    }
    __syncthreads();

    // pass 2: scatter (col,val) into LDS run table (src re-read is L2-hot)
    for (int i = tid; i < cnt; i += 512) {
        int2 p = src[i];
        int rl = ((unsigned)p.x) >> 17;
        if ((rl >> 8) == half) {
            int pos = atomicAdd(&cursor[rl & 255], 1);
            if (pos < SCAP) run[pos] = make_int2(p.x & 0x1FFFF, p.y);
        }
    }
    __syncthreads();

    // gather phase: 8 waves x 32 rows
    const int wave = tid >> 6;
    const int lane = tid & 63;
    const float alpha = *alpha_p;
    const int growbase = b * BIN_ROWS + half * HALF_ROWS;

    for (int rr = wave; rr < HALF_ROWS; rr += 8) {
        int grow = growbase + rr;
        if (grow >= M) break;                       // monotone per wave
        int st  = rstart[rr];
        int den = st + hist[rr];
        if (den > SCAP) den = SCAP;                 // overflow guard (astronomical)
        int deg = den - st;

        float4 acc = make_float4(0.f, 0.f, 0.f, 0.f);
        int e = 0;
        for (; e + 8 <= deg; e += 8) {
            int cc[8]; float vv[8];
            #pragma unroll
            for (int j = 0; j < 8; ++j) {
                int2 p = run[st + e + j];           // uniform addr -> broadcast
                cc[j] = p.x; vv[j] = __int_as_float(p.y);
            }
            ushort4 u[8];
            #pragma unroll
            for (int j = 0; j < 8; ++j)
                u[j] = *(const ushort4*)(h + (size_t)cc[j] * H_DIM + lane * 4);
            #pragma unroll
            for (int j = 0; j < 8; ++j) {
                float v = vv[j];
                acc.x += v * bf16_to_f32(u[j].x);
                acc.y += v * bf16_to_f32(u[j].y);
                acc.z += v * bf16_to_f32(u[j].z);
                acc.w += v * bf16_to_f32(u[j].w);
            }
        }
        for (; e < deg; ++e) {
            int2 p = run[st + e];
            float v = __int_as_float(p.y);
            ushort4 u = *(const ushort4*)(h + (size_t)p.x * H_DIM + lane * 4);
            acc.x += v * bf16_to_f32(u.x);
            acc.y += v * bf16_to_f32(u.y);
            acc.z += v * bf16_to_f32(u.z);
            acc.w += v * bf16_to_f32(u.w);
        }

        acc.x = acc.x >= 0.f ? acc.x : alpha * acc.x;
        acc.y = acc.y >= 0.f ? acc.y : alpha * acc.y;
        acc.z = acc.z >= 0.f ? acc.z : alpha * acc.z;
        acc.w = acc.w >= 0.f ? acc.w : alpha * acc.w;
        *(float4*)(out + (size_t)grow * H_DIM + lane * 4) = acc;
    }
}

extern "C" void kernel_launch(void* const* d_in, const int* in_sizes, int n_in,
                              void* d_out, int out_size, void* d_ws, size_t ws_size,
                              hipStream_t stream) {
    const float* x        = (const float*)d_in[0];
    const int*   adj_rows = (const int*)d_in[1];
    const int*   adj_cols = (const int*)d_in[2];
    const float* adj_vals = (const float*)d_in[3];
    const float* W        = (const float*)d_in[4];
    const float* b        = (const float*)d_in[5];
    const float* alpha    = (const float*)d_in[6];
    float* out = (float*)d_out;

    const int M = in_sizes[0] / K_DIM;   // 100000
    const int E = in_sizes[1];           // 3200000
    const int nbins = (M + BIN_ROWS - 1) / BIN_ROWS;   // 196 (<= NBIN_MAX)

    char* ws = (char*)d_ws;
    size_t off = 0;
    auto alloc = [&](size_t bytes) {
        char* p = ws + off;
        off += (bytes + 255) & ~(size_t)255;
        return p;
    };
    unsigned short* h = (unsigned short*)alloc((size_t)M * H_DIM * sizeof(unsigned short)); // 51.2 MB
    int2* binned  = (int2*)alloc((size_t)nbins * EB * sizeof(int2));   // 28.9 MB
    int*  binCursor = (int*)alloc((size_t)NBIN_MAX * sizeof(int));     // 1 KB
    unsigned short* Wbf = (unsigned short*)alloc((size_t)H_DIM * K_DIM * sizeof(unsigned short)); // 256 KB

    // 0) W -> bf16 once
    convert_w_kernel<<<64, 256, 0, stream>>>(W, Wbf);

    // 1) h = bf16( x @ W^T + b )  via MFMA, full H per block
    gemm_bf16_kernel<<<dim3((M + GT_M - 1) / GT_M, 1), 512, 0, stream>>>(x, Wbf, b, h, M);

    // 2) partition edges into 512-row bins (write-combined)
    hipMemsetAsync(binCursor, 0, (size_t)NBIN_MAX * sizeof(int), stream);
    partition_kernel<<<(E + P1_CHUNK - 1) / P1_CHUNK, 512, 0, stream>>>(
        adj_rows, adj_cols, adj_vals, binCursor, binned, E, nbins);

    // 3) fused binsort + SpMM gather + PReLU (block = half-bin)
    spmm_bin_kernel<<<nbins * 2, 512, 0, stream>>>(binned, binCursor, h, alpha, out, M);
}